// Round 7
// baseline (764.563 us; speedup 1.0000x reference)
//
#include <hip/hip_runtime.h>
#include <hip/hip_bf16.h>

typedef __bf16 bf16x8 __attribute__((ext_vector_type(8)));
typedef float f32x4 __attribute__((ext_vector_type(4)));
typedef unsigned short u16x4 __attribute__((ext_vector_type(4)));
typedef unsigned short u16x8 __attribute__((ext_vector_type(8)));

#define B_DIM 8
#define N_SEQ 2048
#define D_DIM 256
#define NB (B_DIM * N_SEQ * D_DIM)   // 4,194,304 elements per tensor
// (1/sqrt(256)) * log2(e)
#define SC_LOG2 0.09016844005556021f
#define DEFER_THR 8.0f

#if __has_builtin(__builtin_amdgcn_exp2f)
#define EXP2F(x) __builtin_amdgcn_exp2f(x)
#else
#define EXP2F(x) exp2f(x)
#endif

__device__ __forceinline__ unsigned short bfbits(float f) {
  return __builtin_bit_cast(unsigned short, (__bf16)f);
}

// ---------------- prep: f32 -> bf16 row-major (xb) + bf16 transposed (xT) ---
// xb[2][B][N][D]: slot0=x1, slot1=x2.   xT[2][B][D][N]: slot0=x2^T, slot1=x1^T
// (xT slot s holds the transpose of the K/V tensor for direction s).
__global__ __launch_bounds__(256)
void prep_cvt_tr(const float* __restrict__ x1, const float* __restrict__ x2,
                 unsigned short* __restrict__ xb, unsigned short* __restrict__ xT) {
  __shared__ unsigned short Lt[64 * 72];   // 64n x 64d tile, stride 72
  const int t   = threadIdx.x;
  const int n0  = blockIdx.x * 64;
  const int d0  = blockIdx.y * 64;
  const int src = blockIdx.z >> 3;
  const int b   = blockIdx.z & 7;
  const float* g = (src ? x2 : x1) + (size_t)b * N_SEQ * D_DIM;
  unsigned short* xbp = xb + (size_t)src * NB + (size_t)b * N_SEQ * D_DIM;
  unsigned short* xTp = xT + (size_t)(src ^ 1) * NB + (size_t)b * D_DIM * N_SEQ;

  #pragma unroll
  for (int r = 0; r < 4; ++r) {
    const int nl = r * 16 + (t >> 4);
    const int dl = (t & 15) * 4;
    float4 v = *(const float4*)(g + (size_t)(n0 + nl) * D_DIM + d0 + dl);
    u16x4 wv;
    wv[0] = bfbits(v.x); wv[1] = bfbits(v.y); wv[2] = bfbits(v.z); wv[3] = bfbits(v.w);
    *(u16x4*)(xbp + (size_t)(n0 + nl) * D_DIM + d0 + dl) = wv;
    *(u16x4*)&Lt[nl * 72 + dl] = wv;
  }
  __syncthreads();
  #pragma unroll
  for (int r = 0; r < 4; ++r) {
    const int dl = r * 16 + (t >> 4);
    const int nl = (t & 15) * 4;
    u16x4 ov;
    ov[0] = Lt[(nl + 0) * 72 + dl];
    ov[1] = Lt[(nl + 1) * 72 + dl];
    ov[2] = Lt[(nl + 2) * 72 + dl];
    ov[3] = Lt[(nl + 3) * 72 + dl];
    *(u16x4*)(xTp + (size_t)(d0 + dl) * N_SEQ + n0 + nl) = ov;
  }
}

// ---------------- combine: out += ws1 ---------------------------------------
__global__ __launch_bounds__(256)
void combine_add(float* __restrict__ out, const float* __restrict__ o1) {
  size_t i = (size_t)blockIdx.x * 256 + threadIdx.x;
  float4 v = ((const float4*)out)[i];
  float4 w = ((const float4*)o1)[i];
  v.x += w.x; v.y += w.y; v.z += w.z; v.w += w.w;
  ((float4*)out)[i] = v;
}

// ---------------- main attention v4 -----------------------------------------
// 1 wave per block (64 threads), 2048 blocks. No LDS, no barriers: each wave
// owns 16 q rows, loops all KV in tiles of 64, reads K from xb and V^T from
// xT directly (L2-resident via XCD-aware block decode). Defer-max softmax.
__global__ __launch_bounds__(64)
void mca_attn_v4(const unsigned short* __restrict__ xb,
                 const unsigned short* __restrict__ xT,
                 float* __restrict__ out0, float* __restrict__ out1) {
  // XCD-aware decode: id%8 = XCD (round-robin dispatch heuristic). Each XCD
  // gets 2 (b,dir) pairs -> hot K/V (+Q, shared tensors) = 4MB = one L2.
  const int id   = blockIdx.x;
  const int xcd  = id & 7;
  const int ord  = id >> 3;            // 0..255
  const int pair = xcd * 2 + (ord >> 7);  // 0..15
  const int qt   = ord & 127;          // q-tile (16 rows each)
  const int dir  = pair & 1;
  const int b    = pair >> 1;

  const unsigned short* Qb  = xb + (size_t)dir * NB + (size_t)b * N_SEQ * D_DIM;
  const unsigned short* Kb  = xb + (size_t)(dir ^ 1) * NB + (size_t)b * N_SEQ * D_DIM;
  const unsigned short* VTg = xT + (size_t)dir * NB + (size_t)b * D_DIM * N_SEQ;
  float* outg = (dir ? out1 : out0) + (size_t)b * N_SEQ * D_DIM;

  const int l  = threadIdx.x;
  const int lr = l & 15;   // A-row / B-col lane index
  const int lg = l >> 4;   // k-group

  const int row0 = qt * 16;

  // Q fragments: qf[kt][j] = Q[row0+lr][kt*32+lg*8+j]
  bf16x8 qf[8];
  {
    const unsigned short* qrow = Qb + (size_t)(row0 + lr) * D_DIM + lg * 8;
    #pragma unroll
    for (int kt = 0; kt < 8; ++kt)
      qf[kt] = *(const bf16x8*)(qrow + kt * 32);
  }

  f32x4 oacc[16];
  #pragma unroll
  for (int i = 0; i < 16; ++i) oacc[i] = (f32x4){0.f, 0.f, 0.f, 0.f};
  float m_run = -1e30f;
  float l_run = 0.0f;

  for (int t = 0; t < N_SEQ / 64; ++t) {
    const int kv0 = t * 64;

    // ---- QK: lane holds S[q=lr][kv = 16*mt + 4*lg + r] --------------------
    f32x4 tacc[4];
    #pragma unroll
    for (int mt = 0; mt < 4; ++mt) tacc[mt] = (f32x4){0.f, 0.f, 0.f, 0.f};
    __builtin_amdgcn_s_setprio(1);
    #pragma unroll
    for (int kt = 0; kt < 8; ++kt) {
      #pragma unroll
      for (int mt = 0; mt < 4; ++mt) {
        bf16x8 kf = *(const bf16x8*)(Kb + (size_t)(kv0 + mt * 16 + lr) * D_DIM
                                        + kt * 32 + lg * 8);
        tacc[mt] = __builtin_amdgcn_mfma_f32_16x16x32_bf16(kf, qf[kt], tacc[mt], 0, 0, 0);
      }
    }
    __builtin_amdgcn_s_setprio(0);

    // ---- softmax with defer-max (per lane: q row = lr) --------------------
    float p[4][4];
    #pragma unroll
    for (int mt = 0; mt < 4; ++mt)
      #pragma unroll
      for (int r = 0; r < 4; ++r)
        p[mt][r] = tacc[mt][r] * SC_LOG2;
    // tree max over the 16 local values
    float tm01 = fmaxf(fmaxf(p[0][0], p[0][1]), fmaxf(p[0][2], p[0][3]));
    float tm1  = fmaxf(fmaxf(p[1][0], p[1][1]), fmaxf(p[1][2], p[1][3]));
    float tm2  = fmaxf(fmaxf(p[2][0], p[2][1]), fmaxf(p[2][2], p[2][3]));
    float tm3  = fmaxf(fmaxf(p[3][0], p[3][1]), fmaxf(p[3][2], p[3][3]));
    float tm = fmaxf(fmaxf(tm01, tm1), fmaxf(tm2, tm3));
    tm = fmaxf(tm, __shfl_xor(tm, 16));
    tm = fmaxf(tm, __shfl_xor(tm, 32));

    if (!__all(tm - m_run <= DEFER_THR)) {
      // rescale path (rare after warm-up)
      float m_new = fmaxf(m_run, tm);
      float fb = EXP2F(m_run - m_new);
      float fq0 = __shfl(fb, lg * 4 + 0);
      float fq1 = __shfl(fb, lg * 4 + 1);
      float fq2 = __shfl(fb, lg * 4 + 2);
      float fq3 = __shfl(fb, lg * 4 + 3);
      #pragma unroll
      for (int dt = 0; dt < 16; ++dt) {
        f32x4 o = oacc[dt];
        o[0] *= fq0; o[1] *= fq1; o[2] *= fq2; o[3] *= fq3;
        oacc[dt] = o;
      }
      l_run *= fb;
      m_run = m_new;
    }

    float rs = 0.0f;
    #pragma unroll
    for (int mt = 0; mt < 4; ++mt)
      #pragma unroll
      for (int r = 0; r < 4; ++r) {
        float e = EXP2F(p[mt][r] - m_run);   // bounded by 2^DEFER_THR
        p[mt][r] = e;
        rs += e;
      }
    rs += __shfl_xor(rs, 16);
    rs += __shfl_xor(rs, 32);
    l_run += rs;

    // P fragments: pf_h[j] = P[q=lr][kv = 32h + 16*(j>=4) + 4*lg + (j&3)]
    bf16x8 pf0, pf1;
    #pragma unroll
    for (int r = 0; r < 4; ++r) {
      pf0[r]     = (__bf16)p[0][r];
      pf0[r + 4] = (__bf16)p[1][r];
      pf1[r]     = (__bf16)p[2][r];
      pf1[r + 4] = (__bf16)p[3][r];
    }

    // ---- PV: V fragments direct from global xT (same k-slot map as P) -----
    __builtin_amdgcn_s_setprio(1);
    #pragma unroll
    for (int dt = 0; dt < 16; ++dt) {
      const unsigned short* vrow = VTg + (size_t)(dt * 16 + lr) * N_SEQ + kv0 + 4 * lg;
      u16x4 a0 = *(const u16x4*)(vrow);
      u16x4 a1 = *(const u16x4*)(vrow + 16);
      u16x4 a2 = *(const u16x4*)(vrow + 32);
      u16x4 a3 = *(const u16x4*)(vrow + 48);
      u16x8 c0 = {a0[0], a0[1], a0[2], a0[3], a1[0], a1[1], a1[2], a1[3]};
      u16x8 c1 = {a2[0], a2[1], a2[2], a2[3], a3[0], a3[1], a3[2], a3[3]};
      bf16x8 vf0 = __builtin_bit_cast(bf16x8, c0);
      bf16x8 vf1 = __builtin_bit_cast(bf16x8, c1);
      oacc[dt] = __builtin_amdgcn_mfma_f32_16x16x32_bf16(pf0, vf0, oacc[dt], 0, 0, 0);
      oacc[dt] = __builtin_amdgcn_mfma_f32_16x16x32_bf16(pf1, vf1, oacc[dt], 0, 0, 0);
    }
    __builtin_amdgcn_s_setprio(0);
  }

  // ---- epilogue: normalize, plain stores ----
  float inv = 1.0f / l_run;
  float iq0 = __shfl(inv, lg * 4 + 0);
  float iq1 = __shfl(inv, lg * 4 + 1);
  float iq2 = __shfl(inv, lg * 4 + 2);
  float iq3 = __shfl(inv, lg * 4 + 3);
  #pragma unroll
  for (int dt = 0; dt < 16; ++dt) {
    float* o0 = outg + (size_t)(row0 + lg * 4) * D_DIM + dt * 16 + lr;
    o0[0 * D_DIM] = oacc[dt][0] * iq0;
    o0[1 * D_DIM] = oacc[dt][1] * iq1;
    o0[2 * D_DIM] = oacc[dt][2] * iq2;
    o0[3 * D_DIM] = oacc[dt][3] * iq3;
  }
}

// ---------------- fallback path (round-2, needs 32MB ws) --------------------
__global__ __launch_bounds__(256)
void cvt_bf16(const float* __restrict__ x1, const float* __restrict__ x2,
              unsigned short* __restrict__ dst) {
  size_t i = ((size_t)blockIdx.x * 256 + threadIdx.x) * 8;
  const float* src = (i < (size_t)NB) ? (x1 + i) : (x2 + (i - NB));
  float4 a = *(const float4*)src;
  float4 b = *(const float4*)(src + 4);
  u16x8 o;
  o[0] = bfbits(a.x); o[1] = bfbits(a.y); o[2] = bfbits(a.z); o[3] = bfbits(a.w);
  o[4] = bfbits(b.x); o[5] = bfbits(b.y); o[6] = bfbits(b.z); o[7] = bfbits(b.w);
  *(u16x8*)(dst + i) = o;
}

__global__ __launch_bounds__(256, 2)
void mca_attn_bf16(const unsigned short* __restrict__ xb,
                   float* __restrict__ out0, float* __restrict__ out1) {
  const int b   = blockIdx.y;
  const int dir = blockIdx.z;
  const unsigned short* Qb = xb + (size_t)(dir ? NB : 0) + (size_t)b * N_SEQ * D_DIM;
  const unsigned short* Kb = xb + (size_t)(dir ? 0 : NB) + (size_t)b * N_SEQ * D_DIM;
  float* outg = (dir ? out1 : out0) + (size_t)b * N_SEQ * D_DIM;

  const int tid = threadIdx.x;
  const int w  = tid >> 6;
  const int l  = tid & 63;
  const int lr = l & 15;
  const int lg = l >> 4;

  __shared__ unsigned short Vt[2][D_DIM][32 + 8];
  const int row0 = blockIdx.x * 64 + w * 16;

  bf16x8 qf[8];
  {
    const unsigned short* qrow = Qb + (size_t)(row0 + lr) * D_DIM + lg * 8;
    #pragma unroll
    for (int kt = 0; kt < 8; ++kt)
      qf[kt] = *(const bf16x8*)(qrow + kt * 32);
  }

  f32x4 oacc[16];
  #pragma unroll
  for (int i = 0; i < 16; ++i) oacc[i] = (f32x4){0.f, 0.f, 0.f, 0.f};
  float m_run = -1e30f, l_run = 0.0f;

  u16x8 pk[4];
  const unsigned short* colbase = Kb + tid;

  #pragma unroll
  for (int blk = 0; blk < 4; ++blk)
    #pragma unroll
    for (int j = 0; j < 8; ++j)
      pk[blk][j] = colbase[(size_t)(blk * 8 + j) * D_DIM];
  #pragma unroll
  for (int blk = 0; blk < 4; ++blk)
    *(u16x8*)&Vt[0][tid][blk * 8] = pk[blk];
  __syncthreads();

  int cur = 0;
  for (int t = 0; t < N_SEQ / 32; ++t) {
    const int kv0 = t * 32;
    if (t + 1 < N_SEQ / 32) {
      const unsigned short* col = colbase + (size_t)(kv0 + 32) * D_DIM;
      #pragma unroll
      for (int blk = 0; blk < 4; ++blk)
        #pragma unroll
        for (int j = 0; j < 8; ++j)
          pk[blk][j] = col[(size_t)(blk * 8 + j) * D_DIM];
    }

    f32x4 tacc[2] = {(f32x4){0.f,0.f,0.f,0.f}, (f32x4){0.f,0.f,0.f,0.f}};
    #pragma unroll
    for (int kt = 0; kt < 8; ++kt) {
      #pragma unroll
      for (int mt = 0; mt < 2; ++mt) {
        bf16x8 kf = *(const bf16x8*)(Kb + (size_t)(kv0 + mt * 16 + lr) * D_DIM
                                        + kt * 32 + lg * 8);
        tacc[mt] = __builtin_amdgcn_mfma_f32_16x16x32_bf16(kf, qf[kt], tacc[mt], 0, 0, 0);
      }
    }

    float p[2][4];
    float tm = -1e30f;
    #pragma unroll
    for (int mt = 0; mt < 2; ++mt)
      #pragma unroll
      for (int r = 0; r < 4; ++r) {
        float s = tacc[mt][r] * SC_LOG2;
        p[mt][r] = s;
        tm = fmaxf(tm, s);
      }
    tm = fmaxf(tm, __shfl_xor(tm, 16));
    tm = fmaxf(tm, __shfl_xor(tm, 32));
    float m_new = fmaxf(m_run, tm);
    float fb = EXP2F(m_run - m_new);
    float rs = 0.0f;
    #pragma unroll
    for (int mt = 0; mt < 2; ++mt)
      #pragma unroll
      for (int r = 0; r < 4; ++r) {
        float e = EXP2F(p[mt][r] - m_new);
        p[mt][r] = e;
        rs += e;
      }
    rs += __shfl_xor(rs, 16);
    rs += __shfl_xor(rs, 32);
    l_run = l_run * fb + rs;
    m_run = m_new;

    float fq0 = __shfl(fb, lg * 4 + 0);
    float fq1 = __shfl(fb, lg * 4 + 1);
    float fq2 = __shfl(fb, lg * 4 + 2);
    float fq3 = __shfl(fb, lg * 4 + 3);
    #pragma unroll
    for (int dt = 0; dt < 16; ++dt) {
      f32x4 o = oacc[dt];
      o[0] *= fq0; o[1] *= fq1; o[2] *= fq2; o[3] *= fq3;
      oacc[dt] = o;
    }

    bf16x8 pf;
    #pragma unroll
    for (int mt = 0; mt < 2; ++mt)
      #pragma unroll
      for (int r = 0; r < 4; ++r)
        pf[mt * 4 + r] = (__bf16)p[mt][r];

    #pragma unroll
    for (int dt = 0; dt < 16; ++dt) {
      u16x4 v0 = *(const u16x4*)&Vt[cur][dt * 16 + lr][lg * 4];
      u16x4 v1 = *(const u16x4*)&Vt[cur][dt * 16 + lr][16 + lg * 4];
      u16x8 vv = {v0[0], v0[1], v0[2], v0[3], v1[0], v1[1], v1[2], v1[3]};
      bf16x8 vf = __builtin_bit_cast(bf16x8, vv);
      oacc[dt] = __builtin_amdgcn_mfma_f32_16x16x32_bf16(pf, vf, oacc[dt], 0, 0, 0);
    }

    if (t + 1 < N_SEQ / 32) {
      #pragma unroll
      for (int blk = 0; blk < 4; ++blk)
        *(u16x8*)&Vt[cur ^ 1][tid][blk * 8] = pk[blk];
    }
    __syncthreads();
    cur ^= 1;
  }

  float inv = 1.0f / l_run;
  float iq0 = __shfl(inv, lg * 4 + 0);
  float iq1 = __shfl(inv, lg * 4 + 1);
  float iq2 = __shfl(inv, lg * 4 + 2);
  float iq3 = __shfl(inv, lg * 4 + 3);
  #pragma unroll
  for (int dt = 0; dt < 16; ++dt) {
    float* o0 = outg + (size_t)(row0 + lg * 4) * D_DIM + dt * 16 + lr;
    o0[0 * D_DIM] = oacc[dt][0] * iq0;
    o0[1 * D_DIM] = oacc[dt][1] * iq1;
    o0[2 * D_DIM] = oacc[dt][2] * iq2;
    o0[3 * D_DIM] = oacc[dt][3] * iq3;
  }
}

extern "C" void kernel_launch(void* const* d_in, const int* in_sizes, int n_in,
                              void* d_out, int out_size, void* d_ws, size_t ws_size,
                              hipStream_t stream) {
  const float* x1 = (const float*)d_in[0];
  const float* x2 = (const float*)d_in[1];
  float* out = (float*)d_out;

  const size_t xb_b  = (size_t)2 * NB * sizeof(unsigned short); // 16 MiB
  const size_t xT_b  = (size_t)2 * NB * sizeof(unsigned short); // 16 MiB
  const size_t o1_b  = (size_t)NB * sizeof(float);              // 16 MiB

  if (ws_size >= xb_b + xT_b + o1_b) {
    unsigned short* xb = (unsigned short*)d_ws;
    unsigned short* xT = (unsigned short*)((char*)d_ws + xb_b);
    float* out1 = (float*)((char*)d_ws + xb_b + xT_b);

    prep_cvt_tr<<<dim3(N_SEQ / 64, D_DIM / 64, 16), 256, 0, stream>>>(x1, x2, xb, xT);
    mca_attn_v4<<<dim3(2048), 64, 0, stream>>>(xb, xT, out, out1);
    combine_add<<<(NB / 4) / 256, 256, 0, stream>>>(out, out1);
  } else {
    unsigned short* xb = (unsigned short*)d_ws;
    float* out1 = (float*)((char*)d_ws + xb_b);
    cvt_bf16<<<(2 * NB) / (256 * 8), 256, 0, stream>>>(x1, x2, xb);
    mca_attn_bf16<<<dim3(N_SEQ / 64, B_DIM, 2), 256, 0, stream>>>(xb, out, out1);
    combine_add<<<(NB / 4) / 256, 256, 0, stream>>>(out, out1);
  }
}

// Round 11
// 276.098 us; speedup vs baseline: 2.7692x; 2.7692x over previous
//
#include <hip/hip_runtime.h>
#include <hip/hip_bf16.h>

typedef __bf16 bf16x8 __attribute__((ext_vector_type(8)));
typedef float f32x4 __attribute__((ext_vector_type(4)));
typedef unsigned short u16x4 __attribute__((ext_vector_type(4)));
typedef unsigned short u16x8 __attribute__((ext_vector_type(8)));

#define B_DIM 8
#define N_SEQ 2048
#define D_DIM 256
#define KVB 32
#define NB (B_DIM * N_SEQ * D_DIM)   // 4,194,304 elements per tensor
// (1/sqrt(256)) * log2(e)
#define SC_LOG2 0.09016844005556021f
#define DEFER_THR 8.0f

#if __has_builtin(__builtin_amdgcn_exp2f)
#define EXP2F(x) __builtin_amdgcn_exp2f(x)
#else
#define EXP2F(x) exp2f(x)
#endif

__device__ __forceinline__ unsigned short bfbits(float f) {
  return __builtin_bit_cast(unsigned short, (__bf16)f);
}

// ---------------- prep: f32 -> bf16 row-major (xb) + bf16 transposed (xT) ---
// xb[2][B][N][D]: slot0=x1, slot1=x2.   xT[2][B][D][N]: slot0=x2^T, slot1=x1^T
// (xT slot s holds the transpose of the K/V tensor for direction s).
__global__ __launch_bounds__(256)
void prep_cvt_tr(const float* __restrict__ x1, const float* __restrict__ x2,
                 unsigned short* __restrict__ xb, unsigned short* __restrict__ xT) {
  __shared__ unsigned short Lt[64 * 72];   // 64n x 64d tile, stride 72
  const int t   = threadIdx.x;
  const int n0  = blockIdx.x * 64;
  const int d0  = blockIdx.y * 64;
  const int src = blockIdx.z >> 3;
  const int b   = blockIdx.z & 7;
  const float* g = (src ? x2 : x1) + (size_t)b * N_SEQ * D_DIM;
  unsigned short* xbp = xb + (size_t)src * NB + (size_t)b * N_SEQ * D_DIM;
  unsigned short* xTp = xT + (size_t)(src ^ 1) * NB + (size_t)b * D_DIM * N_SEQ;

  #pragma unroll
  for (int r = 0; r < 4; ++r) {
    const int nl = r * 16 + (t >> 4);
    const int dl = (t & 15) * 4;
    float4 v = *(const float4*)(g + (size_t)(n0 + nl) * D_DIM + d0 + dl);
    u16x4 wv;
    wv[0] = bfbits(v.x); wv[1] = bfbits(v.y); wv[2] = bfbits(v.z); wv[3] = bfbits(v.w);
    *(u16x4*)(xbp + (size_t)(n0 + nl) * D_DIM + d0 + dl) = wv;
    *(u16x4*)&Lt[nl * 72 + dl] = wv;
  }
  __syncthreads();
  #pragma unroll
  for (int r = 0; r < 4; ++r) {
    const int dl = r * 16 + (t >> 4);
    const int nl = (t & 15) * 4;
    u16x4 ov;
    ov[0] = Lt[(nl + 0) * 72 + dl];
    ov[1] = Lt[(nl + 1) * 72 + dl];
    ov[2] = Lt[(nl + 2) * 72 + dl];
    ov[3] = Lt[(nl + 3) * 72 + dl];
    *(u16x4*)(xTp + (size_t)(d0 + dl) * N_SEQ + n0 + nl) = ov;
  }
}

// ---------------- combine: out += ws1 ---------------------------------------
__global__ __launch_bounds__(256)
void combine_add(float* __restrict__ out, const float* __restrict__ o1) {
  size_t i = (size_t)blockIdx.x * 256 + threadIdx.x;
  float4 v = ((const float4*)out)[i];
  float4 w = ((const float4*)o1)[i];
  v.x += w.x; v.y += w.y; v.z += w.z; v.w += w.w;
  ((float4*)out)[i] = v;
}

// ---------------- async staging (KVB=32 tiles) ------------------------------
// K tile: 32 rows x 256 d bf16 = 16KB. LDS[r][g'] = K[kv0+r][8*(g'^(r&7))..]
// (granule = 16B = 8 elems; XOR swizzle pre-applied to GLOBAL source).
__device__ __forceinline__ void stageK32(const unsigned short* __restrict__ Kb,
                                         unsigned short* dst, int kv0,
                                         int w, int l) {
  const int rsub = l >> 5;          // 0..1
  const int sg   = l & 31;          // dest granule within row
  #pragma unroll
  for (int k = 0; k < 4; ++k) {
    const int i   = w * 4 + k;      // 0..15 over the block
    const int row = 2 * i + rsub;
    const unsigned short* src = Kb + (size_t)(kv0 + row) * D_DIM + ((sg ^ (row & 7)) * 8);
    __builtin_amdgcn_global_load_lds(
        (const __attribute__((address_space(1))) unsigned int*)src,
        (__attribute__((address_space(3))) unsigned int*)(dst + i * 512), 16, 0, 0);
  }
}

// V^T tile: 256 d x 32 kv bf16 = 16KB. LDS[d][g'] = VT[d][kv0 + 8*(g'^(d&3))..]
__device__ __forceinline__ void stageV32(const unsigned short* __restrict__ VTg,
                                         unsigned short* dst, int kv0,
                                         int w, int l) {
  const int dsub = l >> 2;          // 0..15
  const int g    = l & 3;           // dest granule within row
  #pragma unroll
  for (int k = 0; k < 4; ++k) {
    const int i = w * 4 + k;        // 0..15
    const int d = i * 16 + dsub;
    const unsigned short* src = VTg + (size_t)d * N_SEQ + kv0 + ((g ^ (d & 3)) * 8);
    __builtin_amdgcn_global_load_lds(
        (const __attribute__((address_space(1))) unsigned int*)src,
        (__attribute__((address_space(3))) unsigned int*)(dst + i * 512), 16, 0, 0);
  }
}

// ---------------- main attention v5 -----------------------------------------
// 512 blocks x 256 thr (4 waves, 16 q-rows each). KVB=32, K AND V staged in
// LDS (double-buffered, async gload_lds, XOR-swizzled). One barrier per tile.
// XCD-aware block decode keeps each XCD's K/V working set (4MB) in its L2.
__global__ __launch_bounds__(256, 2)
void mca_attn_v5(const unsigned short* __restrict__ xb,
                 const unsigned short* __restrict__ xT,
                 float* __restrict__ out0, float* __restrict__ out1) {
  // decode: id&7 = XCD; each XCD owns 2 consecutive pairs (same b, both dirs)
  const int id   = blockIdx.x;
  const int xcd  = id & 7;
  const int ord  = id >> 3;             // 0..63
  const int pair = xcd * 2 + (ord >> 5);  // 0..15
  const int qt   = ord & 31;            // 32 q-tiles x 64 rows
  const int dir  = pair & 1;
  const int b    = pair >> 1;

  const unsigned short* Qb  = xb + (size_t)dir * NB + (size_t)b * N_SEQ * D_DIM;
  const unsigned short* Kb  = xb + (size_t)(dir ^ 1) * NB + (size_t)b * N_SEQ * D_DIM;
  const unsigned short* VTg = xT + (size_t)dir * NB + (size_t)b * D_DIM * N_SEQ;
  float* outg = (dir ? out1 : out0) + (size_t)b * N_SEQ * D_DIM;

  const int tid = threadIdx.x;
  const int w  = tid >> 6;
  const int l  = tid & 63;
  const int lr = l & 15;   // A-row / B-col lane index
  const int lg = l >> 4;   // k-group

  __shared__ unsigned short Kl[2][KVB * D_DIM];   // 2 x 16KB
  __shared__ unsigned short Vl[2][D_DIM * KVB];   // 2 x 16KB

  const int row0 = qt * 64 + w * 16;

  // Q fragments: qf[kt][j] = Q[row0+lr][kt*32+lg*8+j]
  bf16x8 qf[8];
  {
    const unsigned short* qrow = Qb + (size_t)(row0 + lr) * D_DIM + lg * 8;
    #pragma unroll
    for (int kt = 0; kt < 8; ++kt)
      qf[kt] = *(const bf16x8*)(qrow + kt * 32);
  }

  f32x4 oacc[16];
  #pragma unroll
  for (int i = 0; i < 16; ++i) oacc[i] = (f32x4){0.f, 0.f, 0.f, 0.f};
  float m_run = -1e30f;
  float l_run = 0.0f;

  // prologue: stage tile 0
  stageK32(Kb, &Kl[0][0], 0, w, l);
  stageV32(VTg, &Vl[0][0], 0, w, l);

  for (int t = 0; t < N_SEQ / KVB; ++t) {
    const int kv0 = t * KVB;
    const int buf = t & 1;

    // tile t staged (own 8 VMEM drained per wave; barrier makes it global).
    // The barrier also proves all waves are done READING buf^1 (tile t-1),
    // so staging t+1 into buf^1 below is race-free.
    asm volatile("s_waitcnt vmcnt(0)" ::: "memory");
    __builtin_amdgcn_s_barrier();

    if (t + 1 < N_SEQ / KVB) {
      stageK32(Kb, &Kl[buf ^ 1][0], kv0 + KVB, w, l);
      stageV32(VTg, &Vl[buf ^ 1][0], kv0 + KVB, w, l);
    }

    // ---- QK from LDS: lane holds S[q=lr][kv = 16*mt + 4*lg + r] -----------
    f32x4 tacc[2] = {(f32x4){0.f,0.f,0.f,0.f}, (f32x4){0.f,0.f,0.f,0.f}};
    __builtin_amdgcn_s_setprio(1);
    #pragma unroll
    for (int kt = 0; kt < 8; ++kt) {
      #pragma unroll
      for (int mt = 0; mt < 2; ++mt) {
        const int r = mt * 16 + lr;
        bf16x8 kf = *(const bf16x8*)&Kl[buf][r * D_DIM + (((kt * 4 + lg) ^ (lr & 7)) * 8)];
        tacc[mt] = __builtin_amdgcn_mfma_f32_16x16x32_bf16(kf, qf[kt], tacc[mt], 0, 0, 0);
      }
    }
    __builtin_amdgcn_s_setprio(0);

    // ---- softmax with defer-max (per lane: q row = lr) --------------------
    float p[2][4];
    #pragma unroll
    for (int mt = 0; mt < 2; ++mt)
      #pragma unroll
      for (int r = 0; r < 4; ++r)
        p[mt][r] = tacc[mt][r] * SC_LOG2;
    float tm0 = fmaxf(fmaxf(p[0][0], p[0][1]), fmaxf(p[0][2], p[0][3]));
    float tm1 = fmaxf(fmaxf(p[1][0], p[1][1]), fmaxf(p[1][2], p[1][3]));
    float tm = fmaxf(tm0, tm1);
    tm = fmaxf(tm, __shfl_xor(tm, 16));
    tm = fmaxf(tm, __shfl_xor(tm, 32));

    if (!__all(tm - m_run <= DEFER_THR)) {
      float m_new = fmaxf(m_run, tm);
      float fb = EXP2F(m_run - m_new);
      float fq0 = __shfl(fb, lg * 4 + 0);
      float fq1 = __shfl(fb, lg * 4 + 1);
      float fq2 = __shfl(fb, lg * 4 + 2);
      float fq3 = __shfl(fb, lg * 4 + 3);
      #pragma unroll
      for (int dt = 0; dt < 16; ++dt) {
        f32x4 o = oacc[dt];
        o[0] *= fq0; o[1] *= fq1; o[2] *= fq2; o[3] *= fq3;
        oacc[dt] = o;
      }
      l_run *= fb;
      m_run = m_new;
    }

    float rs = 0.0f;
    #pragma unroll
    for (int mt = 0; mt < 2; ++mt)
      #pragma unroll
      for (int r = 0; r < 4; ++r) {
        float e = EXP2F(p[mt][r] - m_run);   // bounded by 2^DEFER_THR
        p[mt][r] = e;
        rs += e;
      }
    rs += __shfl_xor(rs, 16);
    rs += __shfl_xor(rs, 32);
    l_run += rs;

    // P fragment: pf[j] = P[q=lr][kv = 16*(j>=4) + 4*lg + (j&3)]
    bf16x8 pf;
    #pragma unroll
    for (int r = 0; r < 4; ++r) {
      pf[r]     = (__bf16)p[0][r];
      pf[r + 4] = (__bf16)p[1][r];
    }

    // ---- PV from LDS: vf[j] = V[kv = 16*(j>=4)+4*lg+(j&3)][d=dt*16+lr] ----
    __builtin_amdgcn_s_setprio(1);
    #pragma unroll
    for (int dt = 0; dt < 16; ++dt) {
      const int d  = dt * 16 + lr;
      const int rb = d * KVB;
      const int o8 = (lg & 1) * 4;                 // offset within granule
      u16x4 v0 = *(const u16x4*)&Vl[buf][rb + ((((lg >> 1))     ^ (d & 3)) * 8) + o8];
      u16x4 v1 = *(const u16x4*)&Vl[buf][rb + (((2 + (lg >> 1)) ^ (d & 3)) * 8) + o8];
      u16x8 c = {v0[0], v0[1], v0[2], v0[3], v1[0], v1[1], v1[2], v1[3]};
      bf16x8 vf = __builtin_bit_cast(bf16x8, c);
      oacc[dt] = __builtin_amdgcn_mfma_f32_16x16x32_bf16(pf, vf, oacc[dt], 0, 0, 0);
    }
    __builtin_amdgcn_s_setprio(0);
  }

  // ---- epilogue: normalize, plain stores ----
  float inv = 1.0f / l_run;
  float iq0 = __shfl(inv, lg * 4 + 0);
  float iq1 = __shfl(inv, lg * 4 + 1);
  float iq2 = __shfl(inv, lg * 4 + 2);
  float iq3 = __shfl(inv, lg * 4 + 3);
  #pragma unroll
  for (int dt = 0; dt < 16; ++dt) {
    float* o0 = outg + (size_t)(row0 + lg * 4) * D_DIM + dt * 16 + lr;
    o0[0 * D_DIM] = oacc[dt][0] * iq0;
    o0[1 * D_DIM] = oacc[dt][1] * iq1;
    o0[2 * D_DIM] = oacc[dt][2] * iq2;
    o0[3 * D_DIM] = oacc[dt][3] * iq3;
  }
}

// ---------------- fallback path (round-2, needs 32MB ws) --------------------
__global__ __launch_bounds__(256)
void cvt_bf16(const float* __restrict__ x1, const float* __restrict__ x2,
              unsigned short* __restrict__ dst) {
  size_t i = ((size_t)blockIdx.x * 256 + threadIdx.x) * 8;
  const float* src = (i < (size_t)NB) ? (x1 + i) : (x2 + (i - NB));
  float4 a = *(const float4*)src;
  float4 b = *(const float4*)(src + 4);
  u16x8 o;
  o[0] = bfbits(a.x); o[1] = bfbits(a.y); o[2] = bfbits(a.z); o[3] = bfbits(a.w);
  o[4] = bfbits(b.x); o[5] = bfbits(b.y); o[6] = bfbits(b.z); o[7] = bfbits(b.w);
  *(u16x8*)(dst + i) = o;
}

__global__ __launch_bounds__(256, 2)
void mca_attn_bf16(const unsigned short* __restrict__ xb,
                   float* __restrict__ out0, float* __restrict__ out1) {
  const int b   = blockIdx.y;
  const int dir = blockIdx.z;
  const unsigned short* Qb = xb + (size_t)(dir ? NB : 0) + (size_t)b * N_SEQ * D_DIM;
  const unsigned short* Kb = xb + (size_t)(dir ? 0 : NB) + (size_t)b * N_SEQ * D_DIM;
  float* outg = (dir ? out1 : out0) + (size_t)b * N_SEQ * D_DIM;

  const int tid = threadIdx.x;
  const int w  = tid >> 6;
  const int l  = tid & 63;
  const int lr = l & 15;
  const int lg = l >> 4;

  __shared__ unsigned short Vt[2][D_DIM][32 + 8];
  const int row0 = blockIdx.x * 64 + w * 16;

  bf16x8 qf[8];
  {
    const unsigned short* qrow = Qb + (size_t)(row0 + lr) * D_DIM + lg * 8;
    #pragma unroll
    for (int kt = 0; kt < 8; ++kt)
      qf[kt] = *(const bf16x8*)(qrow + kt * 32);
  }

  f32x4 oacc[16];
  #pragma unroll
  for (int i = 0; i < 16; ++i) oacc[i] = (f32x4){0.f, 0.f, 0.f, 0.f};
  float m_run = -1e30f, l_run = 0.0f;

  u16x8 pk[4];
  const unsigned short* colbase = Kb + tid;

  #pragma unroll
  for (int blk = 0; blk < 4; ++blk)
    #pragma unroll
    for (int j = 0; j < 8; ++j)
      pk[blk][j] = colbase[(size_t)(blk * 8 + j) * D_DIM];
  #pragma unroll
  for (int blk = 0; blk < 4; ++blk)
    *(u16x8*)&Vt[0][tid][blk * 8] = pk[blk];
  __syncthreads();

  int cur = 0;
  for (int t = 0; t < N_SEQ / 32; ++t) {
    const int kv0 = t * 32;
    if (t + 1 < N_SEQ / 32) {
      const unsigned short* col = colbase + (size_t)(kv0 + 32) * D_DIM;
      #pragma unroll
      for (int blk = 0; blk < 4; ++blk)
        #pragma unroll
        for (int j = 0; j < 8; ++j)
          pk[blk][j] = col[(size_t)(blk * 8 + j) * D_DIM];
    }

    f32x4 tacc[2] = {(f32x4){0.f,0.f,0.f,0.f}, (f32x4){0.f,0.f,0.f,0.f}};
    #pragma unroll
    for (int kt = 0; kt < 8; ++kt) {
      #pragma unroll
      for (int mt = 0; mt < 2; ++mt) {
        bf16x8 kf = *(const bf16x8*)(Kb + (size_t)(kv0 + mt * 16 + lr) * D_DIM
                                        + kt * 32 + lg * 8);
        tacc[mt] = __builtin_amdgcn_mfma_f32_16x16x32_bf16(kf, qf[kt], tacc[mt], 0, 0, 0);
      }
    }

    float p[2][4];
    float tm = -1e30f;
    #pragma unroll
    for (int mt = 0; mt < 2; ++mt)
      #pragma unroll
      for (int r = 0; r < 4; ++r) {
        float s = tacc[mt][r] * SC_LOG2;
        p[mt][r] = s;
        tm = fmaxf(tm, s);
      }
    tm = fmaxf(tm, __shfl_xor(tm, 16));
    tm = fmaxf(tm, __shfl_xor(tm, 32));
    float m_new = fmaxf(m_run, tm);
    float fb = EXP2F(m_run - m_new);
    float rs = 0.0f;
    #pragma unroll
    for (int mt = 0; mt < 2; ++mt)
      #pragma unroll
      for (int r = 0; r < 4; ++r) {
        float e = EXP2F(p[mt][r] - m_new);
        p[mt][r] = e;
        rs += e;
      }
    rs += __shfl_xor(rs, 16);
    rs += __shfl_xor(rs, 32);
    l_run = l_run * fb + rs;
    m_run = m_new;

    float fq0 = __shfl(fb, lg * 4 + 0);
    float fq1 = __shfl(fb, lg * 4 + 1);
    float fq2 = __shfl(fb, lg * 4 + 2);
    float fq3 = __shfl(fb, lg * 4 + 3);
    #pragma unroll
    for (int dt = 0; dt < 16; ++dt) {
      f32x4 o = oacc[dt];
      o[0] *= fq0; o[1] *= fq1; o[2] *= fq2; o[3] *= fq3;
      oacc[dt] = o;
    }

    bf16x8 pf;
    #pragma unroll
    for (int mt = 0; mt < 2; ++mt)
      #pragma unroll
      for (int r = 0; r < 4; ++r)
        pf[mt * 4 + r] = (__bf16)p[mt][r];

    #pragma unroll
    for (int dt = 0; dt < 16; ++dt) {
      u16x4 v0 = *(const u16x4*)&Vt[cur][dt * 16 + lr][lg * 4];
      u16x4 v1 = *(const u16x4*)&Vt[cur][dt * 16 + lr][16 + lg * 4];
      u16x8 vv = {v0[0], v0[1], v0[2], v0[3], v1[0], v1[1], v1[2], v1[3]};
      bf16x8 vf = __builtin_bit_cast(bf16x8, vv);
      oacc[dt] = __builtin_amdgcn_mfma_f32_16x16x32_bf16(pf, vf, oacc[dt], 0, 0, 0);
    }

    if (t + 1 < N_SEQ / 32) {
      #pragma unroll
      for (int blk = 0; blk < 4; ++blk)
        *(u16x8*)&Vt[cur ^ 1][tid][blk * 8] = pk[blk];
    }
    __syncthreads();
    cur ^= 1;
  }

  float inv = 1.0f / l_run;
  float iq0 = __shfl(inv, lg * 4 + 0);
  float iq1 = __shfl(inv, lg * 4 + 1);
  float iq2 = __shfl(inv, lg * 4 + 2);
  float iq3 = __shfl(inv, lg * 4 + 3);
  #pragma unroll
  for (int dt = 0; dt < 16; ++dt) {
    float* o0 = outg + (size_t)(row0 + lg * 4) * D_DIM + dt * 16 + lr;
    o0[0 * D_DIM] = oacc[dt][0] * iq0;
    o0[1 * D_DIM] = oacc[dt][1] * iq1;
    o0[2 * D_DIM] = oacc[dt][2] * iq2;
    o0[3 * D_DIM] = oacc[dt][3] * iq3;
  }
}

extern "C" void kernel_launch(void* const* d_in, const int* in_sizes, int n_in,
                              void* d_out, int out_size, void* d_ws, size_t ws_size,
                              hipStream_t stream) {
  const float* x1 = (const float*)d_in[0];
  const float* x2 = (const float*)d_in[1];
  float* out = (float*)d_out;

  const size_t xb_b  = (size_t)2 * NB * sizeof(unsigned short);
  const size_t xT_b  = (size_t)2 * NB * sizeof(unsigned short);
  const size_t o1_b  = (size_t)NB * sizeof(float);

  if (ws_size >= xb_b + xT_b + o1_b) {
    unsigned short* xb = (unsigned short*)d_ws;
    unsigned short* xT = (unsigned short*)((char*)d_ws + xb_b);
    float* out1 = (float*)((char*)d_ws + xb_b + xT_b);

    prep_cvt_tr<<<dim3(N_SEQ / 64, D_DIM / 64, 16), 256, 0, stream>>>(x1, x2, xb, xT);
    mca_attn_v5<<<dim3(512), 256, 0, stream>>>(xb, xT, out, out1);
    combine_add<<<(NB / 4) / 256, 256, 0, stream>>>(out, out1);
  } else {
    unsigned short* xb = (unsigned short*)d_ws;
    float* out1 = (float*)((char*)d_ws + xb_b);
    cvt_bf16<<<(2 * NB) / (256 * 8), 256, 0, stream>>>(x1, x2, xb);
    mca_attn_bf16<<<dim3(N_SEQ / 64, B_DIM, 2), 256, 0, stream>>>(xb, out, out1);
    combine_add<<<(NB / 4) / 256, 256, 0, stream>>>(out, out1);
  }
}

// Round 13
// 196.257 us; speedup vs baseline: 3.8957x; 1.4068x over previous
//
#include <hip/hip_runtime.h>
#include <hip/hip_bf16.h>

typedef __bf16 bf16x8 __attribute__((ext_vector_type(8)));
typedef float f32x4 __attribute__((ext_vector_type(4)));
typedef unsigned short u16x4 __attribute__((ext_vector_type(4)));
typedef unsigned short u16x8 __attribute__((ext_vector_type(8)));

#define B_DIM 8
#define N_SEQ 2048
#define D_DIM 256
#define KVB 32
#define NB (B_DIM * N_SEQ * D_DIM)   // 4,194,304 elements per tensor
// (1/sqrt(256)) * log2(e)
#define SC_LOG2 0.09016844005556021f
#define DEFER_THR 8.0f

#if __has_builtin(__builtin_amdgcn_exp2f)
#define EXP2F(x) __builtin_amdgcn_exp2f(x)
#else
#define EXP2F(x) exp2f(x)
#endif

__device__ __forceinline__ unsigned short bfbits(float f) {
  return __builtin_bit_cast(unsigned short, (__bf16)f);
}

// ---------------- prep: f32 -> bf16 row-major (xb) + kv-chunked V^T (xTc) ---
// xb[2][B][N][D]: slot0=x1, slot1=x2.
// xTc slot s = K/V tensor of direction s, layout: element (d, kv) at
//   ((kv>>2)*128 + (d>>1))*8 + (d&1)*4 + (kv&3)
// -> each 4-kv "chunk" x 256-d block is 2KB contiguous; a 32-kv tile = 16KB
//    contiguous; PV ds_read banks become 2*lr mod 32 (conflict-free).
__global__ __launch_bounds__(256)
void prep_cvt_chunk(const float* __restrict__ x1, const float* __restrict__ x2,
                    unsigned short* __restrict__ xb, unsigned short* __restrict__ xTc) {
  __shared__ unsigned short Lt[64 * 72];   // 64n x 64d tile, stride 72
  const int t   = threadIdx.x;
  const int n0  = blockIdx.x * 64;
  const int d0  = blockIdx.y * 64;
  const int src = blockIdx.z >> 3;
  const int b   = blockIdx.z & 7;
  const float* g = (src ? x2 : x1) + (size_t)b * N_SEQ * D_DIM;
  unsigned short* xbp  = xb  + (size_t)src * NB + (size_t)b * N_SEQ * D_DIM;
  unsigned short* xTcp = xTc + (size_t)(src ^ 1) * NB + (size_t)b * N_SEQ * D_DIM;

  #pragma unroll
  for (int r = 0; r < 4; ++r) {
    const int nl = r * 16 + (t >> 4);
    const int dl = (t & 15) * 4;
    float4 v = *(const float4*)(g + (size_t)(n0 + nl) * D_DIM + d0 + dl);
    u16x4 wv;
    wv[0] = bfbits(v.x); wv[1] = bfbits(v.y); wv[2] = bfbits(v.z); wv[3] = bfbits(v.w);
    *(u16x4*)(xbp + (size_t)(n0 + nl) * D_DIM + d0 + dl) = wv;
    *(u16x4*)&Lt[nl * 72 + dl] = wv;
  }
  __syncthreads();
  #pragma unroll
  for (int r = 0; r < 4; ++r) {
    const int dl = r * 16 + (t >> 4);   // d within tile
    const int nl = (t & 15) * 4;        // kv chunk base within tile
    u16x4 ov;
    ov[0] = Lt[(nl + 0) * 72 + dl];     // = x[n0+nl+j][d0+dl] = VT[d][kv]
    ov[1] = Lt[(nl + 1) * 72 + dl];
    ov[2] = Lt[(nl + 2) * 72 + dl];
    ov[3] = Lt[(nl + 3) * 72 + dl];
    const int d  = d0 + dl;
    const int kv = n0 + nl;
    *(u16x4*)(xTcp + ((size_t)(kv >> 2) * 128 + (d >> 1)) * 8 + (d & 1) * 4) = ov;
  }
}

// ---------------- combine: out += ws1 ---------------------------------------
__global__ __launch_bounds__(256)
void combine_add(float* __restrict__ out, const float* __restrict__ o1) {
  size_t i = (size_t)blockIdx.x * 256 + threadIdx.x;
  float4 v = ((const float4*)out)[i];
  float4 w = ((const float4*)o1)[i];
  v.x += w.x; v.y += w.y; v.z += w.z; v.w += w.w;
  ((float4*)out)[i] = v;
}

// ---------------- async staging (KVB=32 tiles) ------------------------------
// K tile: 32 rows x 256 d bf16 = 16KB. LDS[r][g'] = K[kv0+r][8*(g'^(r&7))..]
// (granule = 16B = 8 elems; XOR swizzle pre-applied to GLOBAL source).
__device__ __forceinline__ void stageK32(const unsigned short* __restrict__ Kb,
                                         unsigned short* dst, int kv0,
                                         int w, int l) {
  const int rsub = l >> 5;          // 0..1
  const int sg   = l & 31;          // dest granule within row
  #pragma unroll
  for (int k = 0; k < 4; ++k) {
    const int i   = w * 4 + k;      // 0..15 over the block
    const int row = 2 * i + rsub;
    const unsigned short* src = Kb + (size_t)(kv0 + row) * D_DIM + ((sg ^ (row & 7)) * 8);
    __builtin_amdgcn_global_load_lds(
        (const __attribute__((address_space(1))) unsigned int*)src,
        (__attribute__((address_space(3))) unsigned int*)(dst + i * 512), 16, 0, 0);
  }
}

// V tile from xTc: 16KB CONTIGUOUS at VTc + kv0*256. Pure linear copy.
__device__ __forceinline__ void stageV32c(const unsigned short* __restrict__ VTc,
                                          unsigned short* dst, int kv0,
                                          int w, int l) {
  const unsigned short* base = VTc + (size_t)kv0 * 256 + (size_t)l * 8;
  #pragma unroll
  for (int k = 0; k < 4; ++k) {
    const int i = w * 4 + k;        // 0..15: 1KB per instruction
    __builtin_amdgcn_global_load_lds(
        (const __attribute__((address_space(1))) unsigned int*)(base + i * 512),
        (__attribute__((address_space(3))) unsigned int*)(dst + i * 512), 16, 0, 0);
  }
}

// ---------------- main attention v6 -----------------------------------------
// v5 + kv-chunked V layout: PV ds_reads bank = 2*lr mod 32 (conflict-free).
// 512 blocks x 256 thr (4 waves, 16 q-rows each). KVB=32, K+V LDS-staged
// (double-buffered, async gload_lds). One barrier per tile. XCD-aware decode.
__global__ __launch_bounds__(256, 2)
void mca_attn_v6(const unsigned short* __restrict__ xb,
                 const unsigned short* __restrict__ xTc,
                 float* __restrict__ out0, float* __restrict__ out1) {
  // decode: id&7 = XCD; each XCD owns 2 consecutive pairs
  const int id   = blockIdx.x;
  const int xcd  = id & 7;
  const int ord  = id >> 3;             // 0..63
  const int pair = xcd * 2 + (ord >> 5);  // 0..15
  const int qt   = ord & 31;            // 32 q-tiles x 64 rows
  const int dir  = pair & 1;
  const int b    = pair >> 1;

  const unsigned short* Qb  = xb  + (size_t)dir * NB + (size_t)b * N_SEQ * D_DIM;
  const unsigned short* Kb  = xb  + (size_t)(dir ^ 1) * NB + (size_t)b * N_SEQ * D_DIM;
  const unsigned short* VTc = xTc + (size_t)dir * NB + (size_t)b * N_SEQ * D_DIM;
  float* outg = (dir ? out1 : out0) + (size_t)b * N_SEQ * D_DIM;

  const int tid = threadIdx.x;
  const int w  = tid >> 6;
  const int l  = tid & 63;
  const int lr = l & 15;   // A-row / B-col lane index
  const int lg = l >> 4;   // k-group

  __shared__ unsigned short Kl[2][KVB * D_DIM];   // 2 x 16KB
  __shared__ unsigned short Vl[2][D_DIM * KVB];   // 2 x 16KB (chunked layout)

  const int row0 = qt * 64 + w * 16;

  // Q fragments: qf[kt][j] = Q[row0+lr][kt*32+lg*8+j]
  bf16x8 qf[8];
  {
    const unsigned short* qrow = Qb + (size_t)(row0 + lr) * D_DIM + lg * 8;
    #pragma unroll
    for (int kt = 0; kt < 8; ++kt)
      qf[kt] = *(const bf16x8*)(qrow + kt * 32);
  }

  f32x4 oacc[16];
  #pragma unroll
  for (int i = 0; i < 16; ++i) oacc[i] = (f32x4){0.f, 0.f, 0.f, 0.f};
  float m_run = -1e30f;
  float l_run = 0.0f;

  // prologue: stage tile 0
  stageK32(Kb, &Kl[0][0], 0, w, l);
  stageV32c(VTc, &Vl[0][0], 0, w, l);

  for (int t = 0; t < N_SEQ / KVB; ++t) {
    const int kv0 = t * KVB;
    const int buf = t & 1;

    // tile t staged (own 8 VMEM drained; barrier makes it block-global and
    // proves all waves finished reading buf^1 -> staging t+1 is race-free).
    asm volatile("s_waitcnt vmcnt(0)" ::: "memory");
    __builtin_amdgcn_s_barrier();

    if (t + 1 < N_SEQ / KVB) {
      stageK32(Kb, &Kl[buf ^ 1][0], kv0 + KVB, w, l);
      stageV32c(VTc, &Vl[buf ^ 1][0], kv0 + KVB, w, l);
    }

    // ---- QK from LDS: lane holds S[q=lr][kv = 16*mt + 4*lg + r] -----------
    f32x4 tacc[2] = {(f32x4){0.f,0.f,0.f,0.f}, (f32x4){0.f,0.f,0.f,0.f}};
    __builtin_amdgcn_s_setprio(1);
    #pragma unroll
    for (int kt = 0; kt < 8; ++kt) {
      #pragma unroll
      for (int mt = 0; mt < 2; ++mt) {
        const int r = mt * 16 + lr;
        bf16x8 kf = *(const bf16x8*)&Kl[buf][r * D_DIM + (((kt * 4 + lg) ^ (lr & 7)) * 8)];
        tacc[mt] = __builtin_amdgcn_mfma_f32_16x16x32_bf16(kf, qf[kt], tacc[mt], 0, 0, 0);
      }
    }
    __builtin_amdgcn_s_setprio(0);

    // ---- softmax with defer-max (per lane: q row = lr) --------------------
    float p[2][4];
    #pragma unroll
    for (int mt = 0; mt < 2; ++mt)
      #pragma unroll
      for (int r = 0; r < 4; ++r)
        p[mt][r] = tacc[mt][r] * SC_LOG2;
    float tm0 = fmaxf(fmaxf(p[0][0], p[0][1]), fmaxf(p[0][2], p[0][3]));
    float tm1 = fmaxf(fmaxf(p[1][0], p[1][1]), fmaxf(p[1][2], p[1][3]));
    float tm = fmaxf(tm0, tm1);
    tm = fmaxf(tm, __shfl_xor(tm, 16));
    tm = fmaxf(tm, __shfl_xor(tm, 32));

    if (!__all(tm - m_run <= DEFER_THR)) {
      float m_new = fmaxf(m_run, tm);
      float fb = EXP2F(m_run - m_new);
      float fq0 = __shfl(fb, lg * 4 + 0);
      float fq1 = __shfl(fb, lg * 4 + 1);
      float fq2 = __shfl(fb, lg * 4 + 2);
      float fq3 = __shfl(fb, lg * 4 + 3);
      #pragma unroll
      for (int dt = 0; dt < 16; ++dt) {
        f32x4 o = oacc[dt];
        o[0] *= fq0; o[1] *= fq1; o[2] *= fq2; o[3] *= fq3;
        oacc[dt] = o;
      }
      l_run *= fb;
      m_run = m_new;
    }

    float rs = 0.0f;
    #pragma unroll
    for (int mt = 0; mt < 2; ++mt)
      #pragma unroll
      for (int r = 0; r < 4; ++r) {
        float e = EXP2F(p[mt][r] - m_run);   // bounded by 2^DEFER_THR
        p[mt][r] = e;
        rs += e;
      }
    rs += __shfl_xor(rs, 16);
    rs += __shfl_xor(rs, 32);
    l_run += rs;

    // P fragment: pf[j] = P[q=lr][kv = 16*(j>=4) + 4*lg + (j&3)]
    bf16x8 pf;
    #pragma unroll
    for (int r = 0; r < 4; ++r) {
      pf[r]     = (__bf16)p[0][r];
      pf[r + 4] = (__bf16)p[1][r];
    }

    // ---- PV from chunked LDS: vf[j] = V[kv = 16*(j>=4)+4*lg+(j&3)][d] -----
    // chunk c holds kv = 4c..4c+3; lane reads chunks (lg, 4+lg) at
    // offset dt*64 + lr*4  -> bank = 2*lr mod 32: conflict-free.
    __builtin_amdgcn_s_setprio(1);
    #pragma unroll
    for (int dt = 0; dt < 16; ++dt) {
      const int vb = dt * 64 + lr * 4;
      u16x4 v0 = *(const u16x4*)&Vl[buf][lg * 1024 + vb];
      u16x4 v1 = *(const u16x4*)&Vl[buf][(4 + lg) * 1024 + vb];
      u16x8 c = {v0[0], v0[1], v0[2], v0[3], v1[0], v1[1], v1[2], v1[3]};
      bf16x8 vf = __builtin_bit_cast(bf16x8, c);
      oacc[dt] = __builtin_amdgcn_mfma_f32_16x16x32_bf16(pf, vf, oacc[dt], 0, 0, 0);
    }
    __builtin_amdgcn_s_setprio(0);
  }

  // ---- epilogue: normalize, plain stores ----
  float inv = 1.0f / l_run;
  float iq0 = __shfl(inv, lg * 4 + 0);
  float iq1 = __shfl(inv, lg * 4 + 1);
  float iq2 = __shfl(inv, lg * 4 + 2);
  float iq3 = __shfl(inv, lg * 4 + 3);
  #pragma unroll
  for (int dt = 0; dt < 16; ++dt) {
    float* o0 = outg + (size_t)(row0 + lg * 4) * D_DIM + dt * 16 + lr;
    o0[0 * D_DIM] = oacc[dt][0] * iq0;
    o0[1 * D_DIM] = oacc[dt][1] * iq1;
    o0[2 * D_DIM] = oacc[dt][2] * iq2;
    o0[3 * D_DIM] = oacc[dt][3] * iq3;
  }
}

// ---------------- fallback path (round-2, needs 32MB ws) --------------------
__global__ __launch_bounds__(256)
void cvt_bf16(const float* __restrict__ x1, const float* __restrict__ x2,
              unsigned short* __restrict__ dst) {
  size_t i = ((size_t)blockIdx.x * 256 + threadIdx.x) * 8;
  const float* src = (i < (size_t)NB) ? (x1 + i) : (x2 + (i - NB));
  float4 a = *(const float4*)src;
  float4 b = *(const float4*)(src + 4);
  u16x8 o;
  o[0] = bfbits(a.x); o[1] = bfbits(a.y); o[2] = bfbits(a.z); o[3] = bfbits(a.w);
  o[4] = bfbits(b.x); o[5] = bfbits(b.y); o[6] = bfbits(b.z); o[7] = bfbits(b.w);
  *(u16x8*)(dst + i) = o;
}

__global__ __launch_bounds__(256, 2)
void mca_attn_bf16(const unsigned short* __restrict__ xb,
                   float* __restrict__ out0, float* __restrict__ out1) {
  const int b   = blockIdx.y;
  const int dir = blockIdx.z;
  const unsigned short* Qb = xb + (size_t)(dir ? NB : 0) + (size_t)b * N_SEQ * D_DIM;
  const unsigned short* Kb = xb + (size_t)(dir ? 0 : NB) + (size_t)b * N_SEQ * D_DIM;
  float* outg = (dir ? out1 : out0) + (size_t)b * N_SEQ * D_DIM;

  const int tid = threadIdx.x;
  const int w  = tid >> 6;
  const int l  = tid & 63;
  const int lr = l & 15;
  const int lg = l >> 4;

  __shared__ unsigned short Vt[2][D_DIM][32 + 8];
  const int row0 = blockIdx.x * 64 + w * 16;

  bf16x8 qf[8];
  {
    const unsigned short* qrow = Qb + (size_t)(row0 + lr) * D_DIM + lg * 8;
    #pragma unroll
    for (int kt = 0; kt < 8; ++kt)
      qf[kt] = *(const bf16x8*)(qrow + kt * 32);
  }

  f32x4 oacc[16];
  #pragma unroll
  for (int i = 0; i < 16; ++i) oacc[i] = (f32x4){0.f, 0.f, 0.f, 0.f};
  float m_run = -1e30f, l_run = 0.0f;

  u16x8 pk[4];
  const unsigned short* colbase = Kb + tid;

  #pragma unroll
  for (int blk = 0; blk < 4; ++blk)
    #pragma unroll
    for (int j = 0; j < 8; ++j)
      pk[blk][j] = colbase[(size_t)(blk * 8 + j) * D_DIM];
  #pragma unroll
  for (int blk = 0; blk < 4; ++blk)
    *(u16x8*)&Vt[0][tid][blk * 8] = pk[blk];
  __syncthreads();

  int cur = 0;
  for (int t = 0; t < N_SEQ / 32; ++t) {
    const int kv0 = t * 32;
    if (t + 1 < N_SEQ / 32) {
      const unsigned short* col = colbase + (size_t)(kv0 + 32) * D_DIM;
      #pragma unroll
      for (int blk = 0; blk < 4; ++blk)
        #pragma unroll
        for (int j = 0; j < 8; ++j)
          pk[blk][j] = col[(size_t)(blk * 8 + j) * D_DIM];
    }

    f32x4 tacc[2] = {(f32x4){0.f,0.f,0.f,0.f}, (f32x4){0.f,0.f,0.f,0.f}};
    #pragma unroll
    for (int kt = 0; kt < 8; ++kt) {
      #pragma unroll
      for (int mt = 0; mt < 2; ++mt) {
        bf16x8 kf = *(const bf16x8*)(Kb + (size_t)(kv0 + mt * 16 + lr) * D_DIM
                                        + kt * 32 + lg * 8);
        tacc[mt] = __builtin_amdgcn_mfma_f32_16x16x32_bf16(kf, qf[kt], tacc[mt], 0, 0, 0);
      }
    }

    float p[2][4];
    float tm = -1e30f;
    #pragma unroll
    for (int mt = 0; mt < 2; ++mt)
      #pragma unroll
      for (int r = 0; r < 4; ++r) {
        float s = tacc[mt][r] * SC_LOG2;
        p[mt][r] = s;
        tm = fmaxf(tm, s);
      }
    tm = fmaxf(tm, __shfl_xor(tm, 16));
    tm = fmaxf(tm, __shfl_xor(tm, 32));
    float m_new = fmaxf(m_run, tm);
    float fb = EXP2F(m_run - m_new);
    float rs = 0.0f;
    #pragma unroll
    for (int mt = 0; mt < 2; ++mt)
      #pragma unroll
      for (int r = 0; r < 4; ++r) {
        float e = EXP2F(p[mt][r] - m_new);
        p[mt][r] = e;
        rs += e;
      }
    rs += __shfl_xor(rs, 16);
    rs += __shfl_xor(rs, 32);
    l_run = l_run * fb + rs;
    m_run = m_new;

    float fq0 = __shfl(fb, lg * 4 + 0);
    float fq1 = __shfl(fb, lg * 4 + 1);
    float fq2 = __shfl(fb, lg * 4 + 2);
    float fq3 = __shfl(fb, lg * 4 + 3);
    #pragma unroll
    for (int dt = 0; dt < 16; ++dt) {
      f32x4 o = oacc[dt];
      o[0] *= fq0; o[1] *= fq1; o[2] *= fq2; o[3] *= fq3;
      oacc[dt] = o;
    }

    bf16x8 pf;
    #pragma unroll
    for (int mt = 0; mt < 2; ++mt)
      #pragma unroll
      for (int r = 0; r < 4; ++r)
        pf[mt * 4 + r] = (__bf16)p[mt][r];

    #pragma unroll
    for (int dt = 0; dt < 16; ++dt) {
      u16x4 v0 = *(const u16x4*)&Vt[cur][dt * 16 + lr][lg * 4];
      u16x4 v1 = *(const u16x4*)&Vt[cur][dt * 16 + lr][16 + lg * 4];
      u16x8 vv = {v0[0], v0[1], v0[2], v0[3], v1[0], v1[1], v1[2], v1[3]};
      bf16x8 vf = __builtin_bit_cast(bf16x8, vv);
      oacc[dt] = __builtin_amdgcn_mfma_f32_16x16x32_bf16(pf, vf, oacc[dt], 0, 0, 0);
    }

    if (t + 1 < N_SEQ / 32) {
      #pragma unroll
      for (int blk = 0; blk < 4; ++blk)
        *(u16x8*)&Vt[cur ^ 1][tid][blk * 8] = pk[blk];
    }
    __syncthreads();
    cur ^= 1;
  }

  float inv = 1.0f / l_run;
  float iq0 = __shfl(inv, lg * 4 + 0);
  float iq1 = __shfl(inv, lg * 4 + 1);
  float iq2 = __shfl(inv, lg * 4 + 2);
  float iq3 = __shfl(inv, lg * 4 + 3);
  #pragma unroll
  for (int dt = 0; dt < 16; ++dt) {
    float* o0 = outg + (size_t)(row0 + lg * 4) * D_DIM + dt * 16 + lr;
    o0[0 * D_DIM] = oacc[dt][0] * iq0;
    o0[1 * D_DIM] = oacc[dt][1] * iq1;
    o0[2 * D_DIM] = oacc[dt][2] * iq2;
    o0[3 * D_DIM] = oacc[dt][3] * iq3;
  }
}

extern "C" void kernel_launch(void* const* d_in, const int* in_sizes, int n_in,
                              void* d_out, int out_size, void* d_ws, size_t ws_size,
                              hipStream_t stream) {
  const float* x1 = (const float*)d_in[0];
  const float* x2 = (const float*)d_in[1];
  float* out = (float*)d_out;

  const size_t xb_b  = (size_t)2 * NB * sizeof(unsigned short);
  const size_t xT_b  = (size_t)2 * NB * sizeof(unsigned short);
  const size_t o1_b  = (size_t)NB * sizeof(float);

  if (ws_size >= xb_b + xT_b + o1_b) {
    unsigned short* xb  = (unsigned short*)d_ws;
    unsigned short* xTc = (unsigned short*)((char*)d_ws + xb_b);
    float* out1 = (float*)((char*)d_ws + xb_b + xT_b);

    prep_cvt_chunk<<<dim3(N_SEQ / 64, D_DIM / 64, 16), 256, 0, stream>>>(x1, x2, xb, xTc);
    mca_attn_v6<<<dim3(512), 256, 0, stream>>>(xb, xTc, out, out1);
    combine_add<<<(NB / 4) / 256, 256, 0, stream>>>(out, out1);
  } else {
    unsigned short* xb = (unsigned short*)d_ws;
    float* out1 = (float*)((char*)d_ws + xb_b);
    cvt_bf16<<<(2 * NB) / (256 * 8), 256, 0, stream>>>(x1, x2, xb);
    mca_attn_bf16<<<dim3(N_SEQ / 64, B_DIM, 2), 256, 0, stream>>>(xb, out, out1);
    combine_add<<<(NB / 4) / 256, 256, 0, stream>>>(out, out1);
  }
}